// Round 12
// baseline (992.014 us; speedup 1.0000x reference)
//
#include <hip/hip_runtime.h>
#include <hip/hip_bf16.h>

#define NAGENTS 32768
#define SLAB    65536            // NAGENTS*2
#define SPLIT   1310720          // 20*SLAB
#define SPLIT4  327680           // SPLIT/4
#define PRED    30
#define IN_F    40
#define LN_EPS  1e-5f
#define APB     128              // agents per block
#define NBLK    (NAGENTS/APB)    // 256 = 1 block/CU -> co-resident by construction
#define BTH     1024
#define XSTRIDE 104              // shorts per agent row in Xs (96 used + 8 pad)
#define RSTR    72               // shorts per agent row in Rs (40 data + 24 zero + 8 pad)

typedef short bf16x8 __attribute__((ext_vector_type(8)));
typedef short bf16x4 __attribute__((ext_vector_type(4)));
typedef float f32x4  __attribute__((ext_vector_type(4)));

// cst float offsets (only LN2 folded weights stay in LDS; rest hoisted to regs)
#define C_G2   0      // 128 : g2WT[k*2+d] = ln2g[k]*h2pW[d,k]
#define C_SG2  128    // 2
#define C_B2   130    // 2
#define C_TOT  132

__device__ __forceinline__ float frcp(float x){ return __builtin_amdgcn_rcpf(x); }
__device__ __forceinline__ float fsigmoid(float x){ return frcp(1.f + __expf(-x)); }
__device__ __forceinline__ float ftanh(float x){
    float t = __expf(-2.f*fabsf(x));
    float r = (1.f - t) * frcp(1.f + t);
    return copysignf(r, x);
}
__device__ __forceinline__ float lrelu(float x){ return x > 0.f ? x : 0.01f*x; }
__device__ __forceinline__ short f2bf(float x){
    unsigned u = __float_as_uint(x);
    return (short)((u + 0x7FFFu + ((u>>16)&1u)) >> 16);   // RNE
}
__device__ __forceinline__ float bf2f(short s){
    return __uint_as_float(((unsigned)(unsigned short)s) << 16);
}
__device__ __forceinline__ unsigned pk_bf16(float a, float b){
    __hip_bfloat162 h = __float22bfloat162_rn(float2{a, b});
    return *reinterpret_cast<unsigned*>(&h);
}

__global__ __launch_bounds__(BTH, 4)
void persist_kernel(const float* __restrict__ traj,
                    float* __restrict__ out,
                    const float* __restrict__ dec_h,
                    const float* __restrict__ W_ih, const float* __restrict__ W_hh,
                    const float* __restrict__ b_ih, const float* __restrict__ b_hh,
                    const float* __restrict__ emb_W, const float* __restrict__ emb_b,
                    const float* __restrict__ h2p_W, const float* __restrict__ h2p_b,
                    const float* __restrict__ ln1_g, const float* __restrict__ ln1_b,
                    const float* __restrict__ ln2_g, const float* __restrict__ ln2_b,
                    int* __restrict__ flags)   // ws: flags[b] = # steps block b completed
{
    __shared__ short Rs[APB*RSTR];      // bf16 window rows, A-layout, k-pad zeroed
    __shared__ short Xs[APB*XSTRIDE];   // bf16 A-operand [agent][k]: 0..16 x, 16..80 h, 80..96 zero
    __shared__ float St[APB*2];         // LN1 stats: m, inv per agent
    __shared__ float cst[C_TOT];

    const int tid  = threadIdx.x;
    const int bid  = blockIdx.x;
    const int a0   = bid * APB;
    const int l    = tid & 63;
    const int wv   = tid >> 6;            // 0..15
    const int gang = wv >> 2;             // 0..3 : 32 agents each (gates GEMM)
    const int wvin = wv & 3;
    const int cl   = l & 15;
    const int kb   = l >> 4;
    const int nh   = wvin*16 + cl;        // gate-elem column this lane owns

    // ---- one-time: LN2 folded consts into LDS ----
    if (tid < 128) cst[C_G2 + tid] = ln2_g[tid>>1] * h2p_W[(tid&1)*64 + (tid>>1)];
    if (tid < 2) {
        int d = tid;
        float sg = 0.f, bb = 0.f;
        for (int k = 0; k < 64; ++k) {
            float wf = h2p_W[d*64 + k];
            sg += ln2_g[k] * wf;
            bb += ln2_b[k] * wf;
        }
        cst[C_SG2 + d] = sg;
        cst[C_B2 + d]  = bb + h2p_b[d];
    }

    // ---- one-time: per-lane register constants ----
    float bb_r[4];                        // gate bias for column nh
#pragma unroll
    for (int g = 0; g < 4; ++g) bb_r[g] = b_ih[g*64 + nh] + b_hh[g*64 + nh];

    float sgw_c = 0.f, bw_c = 0.f;        // embedding-epilogue consts for e=cl
    for (int f = 0; f < IN_F; ++f) {
        float wf = emb_W[cl*40 + f];
        sgw_c += ln1_g[f] * wf;
        bw_c  += ln1_b[f] * wf;
    }
    bw_c += emb_b[cl];

    // ---- gates-B fragments (weights), once for all 30 steps ----
    bf16x8 bw[4][3];
#pragma unroll
    for (int g = 0; g < 4; ++g)
#pragma unroll
        for (int ks = 0; ks < 3; ++ks) {
            int n = g*64 + nh;
            bf16x8 v;
#pragma unroll
            for (int j = 0; j < 8; ++j) {
                int k = ks*32 + kb*8 + j;
                float f = 0.f;
                if (k < 16)      f = W_ih[n*16 + k];
                else if (k < 80) f = W_hh[n*64 + (k-16)];
                v[j] = f2bf(f);
            }
            bw[g][ks] = v;
        }

    // ---- embedding-B fragments: B[k=f][n=e] = ln1g[f]*embW[e,f], K-pad 0 ----
    bf16x8 ew[2];
#pragma unroll
    for (int ks = 0; ks < 2; ++ks) {
        bf16x8 v;
#pragma unroll
        for (int j = 0; j < 8; ++j) {
            int k = ks*32 + kb*8 + j;
            float f = (k < IN_F) ? ln1_g[k] * emb_W[cl*40 + k] : 0.f;
            v[j] = f2bf(f);
        }
        ew[ks] = v;
    }

    // ---- init h region of Xs from dec_h; zero pads (written once) ----
    for (int i = tid; i < APB*16; i += BTH) {
        int a = i >> 4, q = i & 15;
        float4 hv = ((const float4*)dec_h)[(a0 + a)*16 + q];
        uint2 pv{ pk_bf16(hv.x, hv.y), pk_bf16(hv.z, hv.w) };
        *(uint2*)&Xs[a*XSTRIDE + 16 + q*4] = pv;
    }
    if (tid < APB*2) {      // Xs k-pad [80,96)
        int a = tid >> 1, hf = tid & 1;
        *(bf16x8*)&Xs[a*XSTRIDE + 80 + hf*8] = bf16x8{0,0,0,0,0,0,0,0};
    }
    for (int i = tid; i < APB*3; i += BTH) {   // Rs k-pad [40,64)
        int a = i / 3, seg = i - a*3;
        *(bf16x8*)&Rs[a*RSTR + 40 + seg*8] = bf16x8{0,0,0,0,0,0,0,0};
    }

    // ---- c state fp32 in registers for all 30 steps ----
    float cs[2][4];
#pragma unroll
    for (int mt = 0; mt < 2; ++mt)
#pragma unroll
        for (int r = 0; r < 4; ++r) cs[mt][r] = 0.f;

    __syncthreads();

    for (int s = 0; s < PRED; ++s) {
        // ---- 1. stage rows, polling exactly the producer of each chunk ----
        // Thread polls flags only for chunks IT loads (acquire orders the
        // subsequent out load); traj-region loads proceed immediately.
        {
            const int Gb4 = s*(SLAB/4) + bid*(APB*IN_F/4);
            for (int i = tid; i < APB*IN_F/4; i += BTH) {    // 1280 float4
                int a = i / 10, f4 = i - a*10;
                int G4 = Gb4 + i;
                float4 v;
                if (G4 < SPLIT4) {
                    v = ((const float4*)traj)[G4];
                } else {
                    int of = G4 - SPLIT4;
                    int t = of >> 14;          // out slab
                    int p = (of >> 6) & 255;   // producer block
                    while (__hip_atomic_load(&flags[p], __ATOMIC_ACQUIRE,
                                             __HIP_MEMORY_SCOPE_AGENT) < t + 1)
                        __builtin_amdgcn_s_sleep(1);
                    v = ((const float4*)out)[of];
                }
                uint2 pv{ pk_bf16(v.x, v.y), pk_bf16(v.z, v.w) };
                *(uint2*)&Rs[a*RSTR + f4*4] = pv;
            }
        }
        __syncthreads();

        // ---- 2a. embedding GEMM (waves 0-7): dacc stays in registers ----
        f32x4 dacc;
        if (wv < 8) {
            dacc = f32x4{0.f, 0.f, 0.f, 0.f};
            const short* base = &Rs[(wv*16 + cl)*RSTR + kb*8];
            bf16x8 a0f = *(const bf16x8*)(base);        // k 0..31
            bf16x8 a1f = *(const bf16x8*)(base + 32);   // k 32..63
            dacc = __builtin_amdgcn_mfma_f32_16x16x32_bf16(a0f, ew[0], dacc, 0, 0, 0);
            dacc = __builtin_amdgcn_mfma_f32_16x16x32_bf16(a1f, ew[1], dacc, 0, 0, 0);
        } else {
        // ---- 2b. LN1 stats (waves 8-15): 4 thr/agent over bf16 rows ----
            int t2 = tid - 512;
            int a = t2 >> 2, p = t2 & 3;
            const bf16x8* rp = (const bf16x8*)&Rs[a*RSTR + p*16];
            bf16x8 v0 = rp[0], v1 = rp[1];    // k-pad zeros don't affect sums
            float s1 = 0.f, s2 = 0.f;
#pragma unroll
            for (int j = 0; j < 8; ++j) {
                float f0 = bf2f(v0[j]), f1 = bf2f(v1[j]);
                s1 += f0 + f1; s2 += f0*f0 + f1*f1;
            }
            s1 += __shfl_xor(s1, 1, 64); s2 += __shfl_xor(s2, 1, 64);
            s1 += __shfl_xor(s1, 2, 64); s2 += __shfl_xor(s2, 2, 64);
            if (p == 0) {
                float m = s1 * (1.f/IN_F);
                St[a*2]   = m;
                St[a*2+1] = rsqrtf(s2*(1.f/IN_F) - m*m + LN_EPS);
            }
        }
        __syncthreads();

        // ---- 3. embedding epilogue (waves 0-7, from registers) -> Xs x ----
        if (wv < 8) {
#pragma unroll
            for (int r = 0; r < 4; ++r) {
                int a = wv*16 + kb*4 + r;
                float m = St[a*2], inv = St[a*2+1];
                float x = inv*(dacc[r] - m*sgw_c) + bw_c;
                Xs[a*XSTRIDE + cl] = f2bf(lrelu(x));
            }
        }
        __syncthreads();

        // ---- 4. gates GEMM via MFMA: gang handles 32 agents, 2 M-tiles ----
        f32x4 acc[2][4];
#pragma unroll
        for (int g = 0; g < 4; ++g) {
            acc[0][g] = f32x4{bb_r[g], bb_r[g], bb_r[g], bb_r[g]};
            acc[1][g] = f32x4{bb_r[g], bb_r[g], bb_r[g], bb_r[g]};
        }
#pragma unroll
        for (int mt = 0; mt < 2; ++mt) {
            const short* base = &Xs[(gang*32 + mt*16 + cl)*XSTRIDE + kb*8];
            bf16x8 af0 = *(const bf16x8*)(base);
            bf16x8 af1 = *(const bf16x8*)(base + 32);
            bf16x8 af2 = *(const bf16x8*)(base + 64);
#pragma unroll
            for (int g = 0; g < 4; ++g) {
                acc[mt][g] = __builtin_amdgcn_mfma_f32_16x16x32_bf16(af0, bw[g][0], acc[mt][g], 0, 0, 0);
                acc[mt][g] = __builtin_amdgcn_mfma_f32_16x16x32_bf16(af1, bw[g][1], acc[mt][g], 0, 0, 0);
                acc[mt][g] = __builtin_amdgcn_mfma_f32_16x16x32_bf16(af2, bw[g][2], acc[mt][g], 0, 0, 0);
            }
        }
        __syncthreads();   // all Xs reads done before h overwrite

        // ---- 5. LSTM elementwise (fast-rcp transcendentals); h -> Xs ----
#pragma unroll
        for (int mt = 0; mt < 2; ++mt) {
            int abase = gang*32 + mt*16 + kb*4;
#pragma unroll
            for (int r = 0; r < 4; ++r) {
                float cn = fsigmoid(acc[mt][1][r]) * cs[mt][r]
                         + fsigmoid(acc[mt][0][r]) * ftanh(acc[mt][2][r]);
                float hn = fsigmoid(acc[mt][3][r]) * ftanh(cn);
                cs[mt][r] = cn;
                Xs[(abase + r)*XSTRIDE + 16 + nh] = f2bf(hn);
            }
        }
        __syncthreads();

        // ---- 6. LN2 (split 8-way) + folded h2p -> out (write-through) ----
        {
            int a = tid >> 3, p = tid & 7;
            bf16x8 hv = *(const bf16x8*)&Xs[a*XSTRIDE + 16 + p*8];
            float s1 = 0.f, s2 = 0.f, d0 = 0.f, d1 = 0.f;
#pragma unroll
            for (int j = 0; j < 8; ++j) {
                float f = bf2f(hv[j]);
                float2 gw = *(const float2*)&cst[C_G2 + (p*8 + j)*2];
                s1 += f; s2 += f*f;
                d0 += f*gw.x; d1 += f*gw.y;
            }
#pragma unroll
            for (int mk = 1; mk < 8; mk <<= 1) {
                s1 += __shfl_xor(s1, mk, 64);
                s2 += __shfl_xor(s2, mk, 64);
                d0 += __shfl_xor(d0, mk, 64);
                d1 += __shfl_xor(d1, mk, 64);
            }
            if (p < 2) {
                float m   = s1 * (1.f/64);
                float inv = rsqrtf(s2*(1.f/64) - m*m + LN_EPS);
                float dd  = (p == 0) ? d0 : d1;
                float val = inv*(dd - m*cst[C_SG2+p]) + cst[C_B2+p];
                __hip_atomic_store(&out[s*SLAB + (a0 + a)*2 + p], val,
                                   __ATOMIC_RELAXED, __HIP_MEMORY_SCOPE_AGENT);
            }
        }

        // ---- 7. publish progress: relaxed flag store after vmcnt drain ----
        if (s != PRED-1) {
            __syncthreads();
            if (tid == 0)
                __hip_atomic_store(&flags[bid], s+1, __ATOMIC_RELAXED,
                                   __HIP_MEMORY_SCOPE_AGENT);
        }
    }
}

extern "C" void kernel_launch(void* const* d_in, const int* in_sizes, int n_in,
                              void* d_out, int out_size, void* d_ws, size_t ws_size,
                              hipStream_t stream) {
    const float* traj  = (const float*)d_in[0];
    // d_in[1] = traj_rel (unused)
    const float* dec_h = (const float*)d_in[2];
    const float* W_ih  = (const float*)d_in[3];
    const float* W_hh  = (const float*)d_in[4];
    const float* b_ih  = (const float*)d_in[5];
    const float* b_hh  = (const float*)d_in[6];
    const float* emb_W = (const float*)d_in[7];
    const float* emb_b = (const float*)d_in[8];
    const float* h2p_W = (const float*)d_in[9];
    const float* h2p_b = (const float*)d_in[10];
    const float* ln1_g = (const float*)d_in[11];
    const float* ln1_b = (const float*)d_in[12];
    const float* ln2_g = (const float*)d_in[13];
    const float* ln2_b = (const float*)d_in[14];
    float* out = (float*)d_out;
    int*   flg = (int*)d_ws;

    persist_kernel<<<NBLK, BTH, 0, stream>>>(
        traj, out, dec_h, W_ih, W_hh, b_ih, b_hh, emb_W, emb_b,
        h2p_W, h2p_b, ln1_g, ln1_b, ln2_g, ln2_b, flg);
}

// Round 13
// 596.529 us; speedup vs baseline: 1.6630x; 1.6630x over previous
//
#include <hip/hip_runtime.h>
#include <hip/hip_bf16.h>

#define NAGENTS 32768
#define SLAB    65536            // NAGENTS*2
#define SPLIT   1310720          // 20*SLAB
#define SPLIT4  327680           // SPLIT/4
#define PRED    30
#define IN_F    40
#define LN_EPS  1e-5f
#define APB     128              // agents per block
#define NBLK    (NAGENTS/APB)    // 256 = 1 block/CU -> co-resident by construction
#define BTH     1024
#define XSTRIDE 104              // shorts per agent row in Xs (96 used + 8 pad)
#define RSTR    72               // shorts per agent row in Rs (40 data + 24 zero + 8 pad)

typedef short bf16x8 __attribute__((ext_vector_type(8)));
typedef short bf16x4 __attribute__((ext_vector_type(4)));
typedef float f32x4  __attribute__((ext_vector_type(4)));

// cst float offsets (only LN2 folded weights in LDS; rest hoisted to regs)
#define C_G2   0      // 128 : g2WT[k*2+d] = ln2g[k]*h2pW[d,k]
#define C_SG2  128    // 2
#define C_B2   130    // 2
#define C_TOT  132

__device__ __forceinline__ float frcp(float x){ return __builtin_amdgcn_rcpf(x); }
__device__ __forceinline__ float fsigmoid(float x){ return frcp(1.f + __expf(-x)); }
__device__ __forceinline__ float ftanh(float x){
    float t = __expf(-2.f*fabsf(x));
    float r = (1.f - t) * frcp(1.f + t);
    return copysignf(r, x);
}
__device__ __forceinline__ float lrelu(float x){ return x > 0.f ? x : 0.01f*x; }
__device__ __forceinline__ short f2bf(float x){
    unsigned u = __float_as_uint(x);
    return (short)((u + 0x7FFFu + ((u>>16)&1u)) >> 16);   // RNE
}
__device__ __forceinline__ float bf2f(short s){
    return __uint_as_float(((unsigned)(unsigned short)s) << 16);
}
__device__ __forceinline__ unsigned pk_bf16(float a, float b){
    __hip_bfloat162 h = __float22bfloat162_rn(float2{a, b});
    return *reinterpret_cast<unsigned*>(&h);
}

__global__ __launch_bounds__(BTH, 4)
void persist_kernel(const float* __restrict__ traj,
                    float* __restrict__ out,
                    const float* __restrict__ dec_h,
                    const float* __restrict__ W_ih, const float* __restrict__ W_hh,
                    const float* __restrict__ b_ih, const float* __restrict__ b_hh,
                    const float* __restrict__ emb_W, const float* __restrict__ emb_b,
                    const float* __restrict__ h2p_W, const float* __restrict__ h2p_b,
                    const float* __restrict__ ln1_g, const float* __restrict__ ln1_b,
                    const float* __restrict__ ln2_g, const float* __restrict__ ln2_b,
                    int* __restrict__ flags)   // ws: flags[b] = # steps block b completed
{
    __shared__ short Rs[APB*RSTR];      // bf16 window rows, A-layout, k-pad zeroed
    __shared__ short Xs[APB*XSTRIDE];   // bf16 A-operand [agent][k]: 0..16 x, 16..80 h, 80..96 zero
    __shared__ float St[APB*2];         // LN1 stats: m, inv per agent
    __shared__ float cst[C_TOT];

    const int tid  = threadIdx.x;
    const int bid  = blockIdx.x;
    const int a0   = bid * APB;
    const int l    = tid & 63;
    const int wv   = tid >> 6;            // 0..15
    const int gang = wv >> 2;             // 0..3 : 32 agents each (gates GEMM)
    const int wvin = wv & 3;
    const int cl   = l & 15;
    const int kb   = l >> 4;
    const int nh   = wvin*16 + cl;        // gate-elem column this lane owns

    // ---- one-time: LN2 folded consts into LDS ----
    if (tid < 128) cst[C_G2 + tid] = ln2_g[tid>>1] * h2p_W[(tid&1)*64 + (tid>>1)];
    if (tid < 2) {
        int d = tid;
        float sg = 0.f, bb = 0.f;
        for (int k = 0; k < 64; ++k) {
            float wf = h2p_W[d*64 + k];
            sg += ln2_g[k] * wf;
            bb += ln2_b[k] * wf;
        }
        cst[C_SG2 + d] = sg;
        cst[C_B2 + d]  = bb + h2p_b[d];
    }

    // ---- one-time: per-lane register constants ----
    float bb_r[4];                        // gate bias for column nh
#pragma unroll
    for (int g = 0; g < 4; ++g) bb_r[g] = b_ih[g*64 + nh] + b_hh[g*64 + nh];

    float sgw_c = 0.f, bw_c = 0.f;        // embedding-epilogue consts for e=cl
    for (int f = 0; f < IN_F; ++f) {
        float wf = emb_W[cl*40 + f];
        sgw_c += ln1_g[f] * wf;
        bw_c  += ln1_b[f] * wf;
    }
    bw_c += emb_b[cl];

    // ---- gates-B fragments (weights), once for all 30 steps ----
    bf16x8 bw[4][3];
#pragma unroll
    for (int g = 0; g < 4; ++g)
#pragma unroll
        for (int ks = 0; ks < 3; ++ks) {
            int n = g*64 + nh;
            bf16x8 v;
#pragma unroll
            for (int j = 0; j < 8; ++j) {
                int k = ks*32 + kb*8 + j;
                float f = 0.f;
                if (k < 16)      f = W_ih[n*16 + k];
                else if (k < 80) f = W_hh[n*64 + (k-16)];
                v[j] = f2bf(f);
            }
            bw[g][ks] = v;
        }

    // ---- embedding-B fragments: B[k=f][n=e] = ln1g[f]*embW[e,f], K-pad 0 ----
    bf16x8 ew[2];
#pragma unroll
    for (int ks = 0; ks < 2; ++ks) {
        bf16x8 v;
#pragma unroll
        for (int j = 0; j < 8; ++j) {
            int k = ks*32 + kb*8 + j;
            float f = (k < IN_F) ? ln1_g[k] * emb_W[cl*40 + k] : 0.f;
            v[j] = f2bf(f);
        }
        ew[ks] = v;
    }

    // ---- init h region of Xs from dec_h; zero pads (written once) ----
    for (int i = tid; i < APB*16; i += BTH) {
        int a = i >> 4, q = i & 15;
        float4 hv = ((const float4*)dec_h)[(a0 + a)*16 + q];
        uint2 pv{ pk_bf16(hv.x, hv.y), pk_bf16(hv.z, hv.w) };
        *(uint2*)&Xs[a*XSTRIDE + 16 + q*4] = pv;
    }
    if (tid < APB*2) {      // Xs k-pad [80,96)
        int a = tid >> 1, hf = tid & 1;
        *(bf16x8*)&Xs[a*XSTRIDE + 80 + hf*8] = bf16x8{0,0,0,0,0,0,0,0};
    }
    for (int i = tid; i < APB*3; i += BTH) {   // Rs k-pad [40,64)
        int a = i / 3, seg = i - a*3;
        *(bf16x8*)&Rs[a*RSTR + 40 + seg*8] = bf16x8{0,0,0,0,0,0,0,0};
    }

    // ---- c state fp32 in registers for all 30 steps ----
    float cs[2][4];
#pragma unroll
    for (int mt = 0; mt < 2; ++mt)
#pragma unroll
        for (int r = 0; r < 4; ++r) cs[mt][r] = 0.f;

    __syncthreads();

    for (int s = 0; s < PRED; ++s) {
        // ---- 0. wait for producer chunks (SEPARATE phase: <=21 acquire polls
        //         per block-step — acquire = cache-inv, keep it OUT of data
        //         loops; round-12 regression proved why) ----
        {
            const long Ob = (long)s*SLAB + (long)a0*IN_F - SPLIT;
            const long Oe = Ob + APB*IN_F;    // exclusive
            if (Oe > 0) {
                long o0 = Ob < 0 ? 0 : Ob;
                int i0 = (int)(o0 >> 8);
                int i1 = (int)((Oe - 1) >> 8);
                for (int i = i0 + tid; i <= i1; i += BTH) {
                    int t = i >> 8, p = i & 255;
                    while (__hip_atomic_load(&flags[p], __ATOMIC_ACQUIRE,
                                             __HIP_MEMORY_SCOPE_AGENT) < t + 1)
                        __builtin_amdgcn_s_sleep(1);
                }
            }
        }
        __syncthreads();

        // ---- 1. stage rows: poll-free float4 loads -> packed bf16 Rs ----
        {
            const int Gb4 = s*(SLAB/4) + bid*(APB*IN_F/4);
            for (int i = tid; i < APB*IN_F/4; i += BTH) {    // 1280 float4
                int a = i / 10, f4 = i - a*10;
                int G4 = Gb4 + i;
                float4 v = (G4 < SPLIT4) ? ((const float4*)traj)[G4]
                                         : ((const float4*)out)[G4 - SPLIT4];
                uint2 pv{ pk_bf16(v.x, v.y), pk_bf16(v.z, v.w) };
                *(uint2*)&Rs[a*RSTR + f4*4] = pv;
            }
        }
        __syncthreads();

        // ---- 2a. embedding GEMM (waves 0-7): dacc stays in registers ----
        f32x4 dacc;
        if (wv < 8) {
            dacc = f32x4{0.f, 0.f, 0.f, 0.f};
            const short* base = &Rs[(wv*16 + cl)*RSTR + kb*8];
            bf16x8 a0f = *(const bf16x8*)(base);        // k 0..31
            bf16x8 a1f = *(const bf16x8*)(base + 32);   // k 32..63
            dacc = __builtin_amdgcn_mfma_f32_16x16x32_bf16(a0f, ew[0], dacc, 0, 0, 0);
            dacc = __builtin_amdgcn_mfma_f32_16x16x32_bf16(a1f, ew[1], dacc, 0, 0, 0);
        } else {
        // ---- 2b. LN1 stats (waves 8-15): 4 thr/agent over bf16 rows ----
            int t2 = tid - 512;
            int a = t2 >> 2, p = t2 & 3;
            const bf16x8* rp = (const bf16x8*)&Rs[a*RSTR + p*16];
            bf16x8 v0 = rp[0], v1 = rp[1];    // k-pad zeros don't affect sums
            float s1 = 0.f, s2 = 0.f;
#pragma unroll
            for (int j = 0; j < 8; ++j) {
                float f0 = bf2f(v0[j]), f1 = bf2f(v1[j]);
                s1 += f0 + f1; s2 += f0*f0 + f1*f1;
            }
            s1 += __shfl_xor(s1, 1, 64); s2 += __shfl_xor(s2, 1, 64);
            s1 += __shfl_xor(s1, 2, 64); s2 += __shfl_xor(s2, 2, 64);
            if (p == 0) {
                float m = s1 * (1.f/IN_F);
                St[a*2]   = m;
                St[a*2+1] = rsqrtf(s2*(1.f/IN_F) - m*m + LN_EPS);
            }
        }
        __syncthreads();

        // ---- 3. embedding epilogue (waves 0-7, from registers) -> Xs x ----
        if (wv < 8) {
#pragma unroll
            for (int r = 0; r < 4; ++r) {
                int a = wv*16 + kb*4 + r;
                float m = St[a*2], inv = St[a*2+1];
                float x = inv*(dacc[r] - m*sgw_c) + bw_c;
                Xs[a*XSTRIDE + cl] = f2bf(lrelu(x));
            }
        }
        __syncthreads();

        // ---- 4. gates GEMM via MFMA: gang handles 32 agents, 2 M-tiles ----
        f32x4 acc[2][4];
#pragma unroll
        for (int g = 0; g < 4; ++g) {
            acc[0][g] = f32x4{bb_r[g], bb_r[g], bb_r[g], bb_r[g]};
            acc[1][g] = f32x4{bb_r[g], bb_r[g], bb_r[g], bb_r[g]};
        }
#pragma unroll
        for (int mt = 0; mt < 2; ++mt) {
            const short* base = &Xs[(gang*32 + mt*16 + cl)*XSTRIDE + kb*8];
            bf16x8 af0 = *(const bf16x8*)(base);
            bf16x8 af1 = *(const bf16x8*)(base + 32);
            bf16x8 af2 = *(const bf16x8*)(base + 64);
#pragma unroll
            for (int g = 0; g < 4; ++g) {
                acc[mt][g] = __builtin_amdgcn_mfma_f32_16x16x32_bf16(af0, bw[g][0], acc[mt][g], 0, 0, 0);
                acc[mt][g] = __builtin_amdgcn_mfma_f32_16x16x32_bf16(af1, bw[g][1], acc[mt][g], 0, 0, 0);
                acc[mt][g] = __builtin_amdgcn_mfma_f32_16x16x32_bf16(af2, bw[g][2], acc[mt][g], 0, 0, 0);
            }
        }
        __syncthreads();   // all Xs reads done before h overwrite

        // ---- 5. LSTM elementwise (fast-rcp transcendentals); h -> Xs ----
#pragma unroll
        for (int mt = 0; mt < 2; ++mt) {
            int abase = gang*32 + mt*16 + kb*4;
#pragma unroll
            for (int r = 0; r < 4; ++r) {
                float cn = fsigmoid(acc[mt][1][r]) * cs[mt][r]
                         + fsigmoid(acc[mt][0][r]) * ftanh(acc[mt][2][r]);
                float hn = fsigmoid(acc[mt][3][r]) * ftanh(cn);
                cs[mt][r] = cn;
                Xs[(abase + r)*XSTRIDE + 16 + nh] = f2bf(hn);
            }
        }
        __syncthreads();

        // ---- 6. LN2 (split 8-way) + folded h2p -> out (write-through) ----
        {
            int a = tid >> 3, p = tid & 7;
            bf16x8 hv = *(const bf16x8*)&Xs[a*XSTRIDE + 16 + p*8];
            float s1 = 0.f, s2 = 0.f, d0 = 0.f, d1 = 0.f;
#pragma unroll
            for (int j = 0; j < 8; ++j) {
                float f = bf2f(hv[j]);
                float2 gw = *(const float2*)&cst[C_G2 + (p*8 + j)*2];
                s1 += f; s2 += f*f;
                d0 += f*gw.x; d1 += f*gw.y;
            }
#pragma unroll
            for (int mk = 1; mk < 8; mk <<= 1) {
                s1 += __shfl_xor(s1, mk, 64);
                s2 += __shfl_xor(s2, mk, 64);
                d0 += __shfl_xor(d0, mk, 64);
                d1 += __shfl_xor(d1, mk, 64);
            }
            if (p < 2) {
                float m   = s1 * (1.f/64);
                float inv = rsqrtf(s2*(1.f/64) - m*m + LN_EPS);
                float dd  = (p == 0) ? d0 : d1;
                float val = inv*(dd - m*cst[C_SG2+p]) + cst[C_B2+p];
                __hip_atomic_store(&out[s*SLAB + (a0 + a)*2 + p], val,
                                   __ATOMIC_RELAXED, __HIP_MEMORY_SCOPE_AGENT);
            }
        }

        // ---- 7. publish progress: relaxed flag store after vmcnt drain ----
        if (s != PRED-1) {
            __syncthreads();
            if (tid == 0)
                __hip_atomic_store(&flags[bid], s+1, __ATOMIC_RELAXED,
                                   __HIP_MEMORY_SCOPE_AGENT);
        }
    }
}

extern "C" void kernel_launch(void* const* d_in, const int* in_sizes, int n_in,
                              void* d_out, int out_size, void* d_ws, size_t ws_size,
                              hipStream_t stream) {
    const float* traj  = (const float*)d_in[0];
    // d_in[1] = traj_rel (unused)
    const float* dec_h = (const float*)d_in[2];
    const float* W_ih  = (const float*)d_in[3];
    const float* W_hh  = (const float*)d_in[4];
    const float* b_ih  = (const float*)d_in[5];
    const float* b_hh  = (const float*)d_in[6];
    const float* emb_W = (const float*)d_in[7];
    const float* emb_b = (const float*)d_in[8];
    const float* h2p_W = (const float*)d_in[9];
    const float* h2p_b = (const float*)d_in[10];
    const float* ln1_g = (const float*)d_in[11];
    const float* ln1_b = (const float*)d_in[12];
    const float* ln2_g = (const float*)d_in[13];
    const float* ln2_b = (const float*)d_in[14];
    float* out = (float*)d_out;
    int*   flg = (int*)d_ws;

    persist_kernel<<<NBLK, BTH, 0, stream>>>(
        traj, out, dec_h, W_ih, W_hh, b_ih, b_hh, emb_W, emb_b,
        h2p_W, h2p_b, ln1_g, ln1_b, ln2_g, ln2_b, flg);
}

// Round 14
// 591.219 us; speedup vs baseline: 1.6779x; 1.0090x over previous
//
#include <hip/hip_runtime.h>
#include <hip/hip_bf16.h>

#define NAGENTS 32768
#define SLAB    65536            // NAGENTS*2
#define SPLIT   1310720          // 20*SLAB
#define SPLIT4  327680           // SPLIT/4
#define PRED    30
#define IN_F    40
#define LN_EPS  1e-5f
#define APB     128              // agents per block
#define NBLK    (NAGENTS/APB)    // 256 = 1 block/CU -> co-resident by construction
#define BTH     1024
#define XSTRIDE 104              // shorts per agent row in Xs (96 used + 8 pad)
#define RSTR    72               // shorts per agent row in Rs (40 data + 24 zero + 8 pad)

typedef short bf16x8 __attribute__((ext_vector_type(8)));
typedef short bf16x4 __attribute__((ext_vector_type(4)));
typedef float f32x4  __attribute__((ext_vector_type(4)));

// cst float offsets (only LN2 folded weights in LDS; rest hoisted to regs)
#define C_G2   0      // 128 : g2WT[k*2+d] = ln2g[k]*h2pW[d,k]
#define C_SG2  128    // 2
#define C_B2   130    // 2
#define C_TOT  132

__device__ __forceinline__ float frcp(float x){ return __builtin_amdgcn_rcpf(x); }
__device__ __forceinline__ float fsigmoid(float x){ return frcp(1.f + __expf(-x)); }
__device__ __forceinline__ float ftanh(float x){
    float t = __expf(-2.f*fabsf(x));
    float r = (1.f - t) * frcp(1.f + t);
    return copysignf(r, x);
}
__device__ __forceinline__ float lrelu(float x){ return x > 0.f ? x : 0.01f*x; }
__device__ __forceinline__ short f2bf(float x){
    unsigned u = __float_as_uint(x);
    return (short)((u + 0x7FFFu + ((u>>16)&1u)) >> 16);   // RNE
}
__device__ __forceinline__ float bf2f(short s){
    return __uint_as_float(((unsigned)(unsigned short)s) << 16);
}
__device__ __forceinline__ unsigned pk_bf16(float a, float b){
    __hip_bfloat162 h = __float22bfloat162_rn(float2{a, b});
    return *reinterpret_cast<unsigned*>(&h);
}

__global__ __launch_bounds__(BTH, 4)
void persist_kernel(const float* __restrict__ traj,
                    float* __restrict__ out,
                    const float* __restrict__ dec_h,
                    const float* __restrict__ W_ih, const float* __restrict__ W_hh,
                    const float* __restrict__ b_ih, const float* __restrict__ b_hh,
                    const float* __restrict__ emb_W, const float* __restrict__ emb_b,
                    const float* __restrict__ h2p_W, const float* __restrict__ h2p_b,
                    const float* __restrict__ ln1_g, const float* __restrict__ ln1_b,
                    const float* __restrict__ ln2_g, const float* __restrict__ ln2_b,
                    int* __restrict__ flags)   // ws: flags[b] = # steps block b completed
{
    __shared__ short Rs[APB*RSTR];      // bf16 window rows, A-layout, k-pad zeroed
    __shared__ short Xs[APB*XSTRIDE];   // bf16 A-operand [agent][k]: 0..16 x, 16..80 h, 80..96 zero
    __shared__ float St[APB*2];         // LN1 stats: m, inv per agent
    __shared__ float cst[C_TOT];

    const int tid  = threadIdx.x;
    const int bid  = blockIdx.x;
    const int a0   = bid * APB;
    const int l    = tid & 63;
    const int wv   = tid >> 6;            // 0..15
    const int gang = wv >> 2;             // 0..3 : 32 agents each (gates GEMM)
    const int wvin = wv & 3;
    const int cl   = l & 15;
    const int kb   = l >> 4;
    const int nh   = wvin*16 + cl;        // gate-elem column this lane owns

    // ---- one-time: LN2 folded consts into LDS ----
    if (tid < 128) cst[C_G2 + tid] = ln2_g[tid>>1] * h2p_W[(tid&1)*64 + (tid>>1)];
    if (tid < 2) {
        int d = tid;
        float sg = 0.f, bb = 0.f;
        for (int k = 0; k < 64; ++k) {
            float wf = h2p_W[d*64 + k];
            sg += ln2_g[k] * wf;
            bb += ln2_b[k] * wf;
        }
        cst[C_SG2 + d] = sg;
        cst[C_B2 + d]  = bb + h2p_b[d];
    }

    // ---- one-time: per-lane register constants ----
    float bb_r[4];                        // gate bias for column nh
#pragma unroll
    for (int g = 0; g < 4; ++g) bb_r[g] = b_ih[g*64 + nh] + b_hh[g*64 + nh];

    float sgw_c = 0.f, bw_c = 0.f;        // embedding-epilogue consts for e=cl
    for (int f = 0; f < IN_F; ++f) {
        float wf = emb_W[cl*40 + f];
        sgw_c += ln1_g[f] * wf;
        bw_c  += ln1_b[f] * wf;
    }
    bw_c += emb_b[cl];

    // ---- gates-B fragments (weights), once for all 30 steps ----
    bf16x8 bw[4][3];
#pragma unroll
    for (int g = 0; g < 4; ++g)
#pragma unroll
        for (int ks = 0; ks < 3; ++ks) {
            int n = g*64 + nh;
            bf16x8 v;
#pragma unroll
            for (int j = 0; j < 8; ++j) {
                int k = ks*32 + kb*8 + j;
                float f = 0.f;
                if (k < 16)      f = W_ih[n*16 + k];
                else if (k < 80) f = W_hh[n*64 + (k-16)];
                v[j] = f2bf(f);
            }
            bw[g][ks] = v;
        }

    // ---- embedding-B fragments: B[k=f][n=e] = ln1g[f]*embW[e,f], K-pad 0 ----
    bf16x8 ew[2];
#pragma unroll
    for (int ks = 0; ks < 2; ++ks) {
        bf16x8 v;
#pragma unroll
        for (int j = 0; j < 8; ++j) {
            int k = ks*32 + kb*8 + j;
            float f = (k < IN_F) ? ln1_g[k] * emb_W[cl*40 + k] : 0.f;
            v[j] = f2bf(f);
        }
        ew[ks] = v;
    }

    // ---- init h region of Xs from dec_h; zero pads (written once) ----
    for (int i = tid; i < APB*16; i += BTH) {
        int a = i >> 4, q = i & 15;
        float4 hv = ((const float4*)dec_h)[(a0 + a)*16 + q];
        uint2 pv{ pk_bf16(hv.x, hv.y), pk_bf16(hv.z, hv.w) };
        *(uint2*)&Xs[a*XSTRIDE + 16 + q*4] = pv;
    }
    if (tid < APB*2) {      // Xs k-pad [80,96)
        int a = tid >> 1, hf = tid & 1;
        *(bf16x8*)&Xs[a*XSTRIDE + 80 + hf*8] = bf16x8{0,0,0,0,0,0,0,0};
    }
    for (int i = tid; i < APB*3; i += BTH) {   // Rs k-pad [40,64)
        int a = i / 3, seg = i - a*3;
        *(bf16x8*)&Rs[a*RSTR + 40 + seg*8] = bf16x8{0,0,0,0,0,0,0,0};
    }

    // ---- c state fp32 in registers for all 30 steps ----
    float cs[2][4];
#pragma unroll
    for (int mt = 0; mt < 2; ++mt)
#pragma unroll
        for (int r = 0; r < 4; ++r) cs[mt][r] = 0.f;

    __syncthreads();

    for (int s = 0; s < PRED; ++s) {
        // ---- 0. wait for producer chunks: RELAXED throttled polls, NO fence.
        // Correctness without acquire: out + flags are written ONLY via
        // agent-scope write-through atomic stores (never dirty in any L2);
        // a consumer L2 line of out can only have been filled by a
        // post-flag read, so no stale copy can exist. Kernel-start cache
        // invalidate covers harness poison. ACQUIRE polls (= buffer_inv per
        // iteration) caused r13's 1.24 GB refetch storm — the invalidation
        // collateral trashed the XCD L2 for all co-resident blocks.
        {
            const long Ob = (long)s*SLAB + (long)a0*IN_F - SPLIT;
            const long Oe = Ob + APB*IN_F;    // exclusive
            if (Oe > 0) {
                long o0 = Ob < 0 ? 0 : Ob;
                int i0 = (int)(o0 >> 8);
                int i1 = (int)((Oe - 1) >> 8);
                for (int i = i0 + tid; i <= i1; i += BTH) {
                    int t = i >> 8, p = i & 255;
                    if (__hip_atomic_load(&flags[p], __ATOMIC_RELAXED,
                                          __HIP_MEMORY_SCOPE_AGENT) >= t + 1)
                        continue;                      // fast path: already done
                    do {
                        __builtin_amdgcn_s_sleep(16);  // ~1024 clk between polls
                    } while (__hip_atomic_load(&flags[p], __ATOMIC_RELAXED,
                                               __HIP_MEMORY_SCOPE_AGENT) < t + 1);
                }
            }
        }
        __syncthreads();

        // ---- 1. stage rows: poll-free float4 loads -> packed bf16 Rs ----
        {
            const int Gb4 = s*(SLAB/4) + bid*(APB*IN_F/4);
            for (int i = tid; i < APB*IN_F/4; i += BTH) {    // 1280 float4
                int a = i / 10, f4 = i - a*10;
                int G4 = Gb4 + i;
                float4 v = (G4 < SPLIT4) ? ((const float4*)traj)[G4]
                                         : ((const float4*)out)[G4 - SPLIT4];
                uint2 pv{ pk_bf16(v.x, v.y), pk_bf16(v.z, v.w) };
                *(uint2*)&Rs[a*RSTR + f4*4] = pv;
            }
        }
        __syncthreads();

        // ---- 2a. embedding GEMM (waves 0-7): dacc stays in registers ----
        f32x4 dacc;
        if (wv < 8) {
            dacc = f32x4{0.f, 0.f, 0.f, 0.f};
            const short* base = &Rs[(wv*16 + cl)*RSTR + kb*8];
            bf16x8 a0f = *(const bf16x8*)(base);        // k 0..31
            bf16x8 a1f = *(const bf16x8*)(base + 32);   // k 32..63
            dacc = __builtin_amdgcn_mfma_f32_16x16x32_bf16(a0f, ew[0], dacc, 0, 0, 0);
            dacc = __builtin_amdgcn_mfma_f32_16x16x32_bf16(a1f, ew[1], dacc, 0, 0, 0);
        } else {
        // ---- 2b. LN1 stats (waves 8-15): 4 thr/agent over bf16 rows ----
            int t2 = tid - 512;
            int a = t2 >> 2, p = t2 & 3;
            const bf16x8* rp = (const bf16x8*)&Rs[a*RSTR + p*16];
            bf16x8 v0 = rp[0], v1 = rp[1];    // k-pad zeros don't affect sums
            float s1 = 0.f, s2 = 0.f;
#pragma unroll
            for (int j = 0; j < 8; ++j) {
                float f0 = bf2f(v0[j]), f1 = bf2f(v1[j]);
                s1 += f0 + f1; s2 += f0*f0 + f1*f1;
            }
            s1 += __shfl_xor(s1, 1, 64); s2 += __shfl_xor(s2, 1, 64);
            s1 += __shfl_xor(s1, 2, 64); s2 += __shfl_xor(s2, 2, 64);
            if (p == 0) {
                float m = s1 * (1.f/IN_F);
                St[a*2]   = m;
                St[a*2+1] = rsqrtf(s2*(1.f/IN_F) - m*m + LN_EPS);
            }
        }
        __syncthreads();

        // ---- 3. embedding epilogue (waves 0-7, from registers) -> Xs x ----
        if (wv < 8) {
#pragma unroll
            for (int r = 0; r < 4; ++r) {
                int a = wv*16 + kb*4 + r;
                float m = St[a*2], inv = St[a*2+1];
                float x = inv*(dacc[r] - m*sgw_c) + bw_c;
                Xs[a*XSTRIDE + cl] = f2bf(lrelu(x));
            }
        }
        __syncthreads();

        // ---- 4. gates GEMM via MFMA: gang handles 32 agents, 2 M-tiles ----
        f32x4 acc[2][4];
#pragma unroll
        for (int g = 0; g < 4; ++g) {
            acc[0][g] = f32x4{bb_r[g], bb_r[g], bb_r[g], bb_r[g]};
            acc[1][g] = f32x4{bb_r[g], bb_r[g], bb_r[g], bb_r[g]};
        }
#pragma unroll
        for (int mt = 0; mt < 2; ++mt) {
            const short* base = &Xs[(gang*32 + mt*16 + cl)*XSTRIDE + kb*8];
            bf16x8 af0 = *(const bf16x8*)(base);
            bf16x8 af1 = *(const bf16x8*)(base + 32);
            bf16x8 af2 = *(const bf16x8*)(base + 64);
#pragma unroll
            for (int g = 0; g < 4; ++g) {
                acc[mt][g] = __builtin_amdgcn_mfma_f32_16x16x32_bf16(af0, bw[g][0], acc[mt][g], 0, 0, 0);
                acc[mt][g] = __builtin_amdgcn_mfma_f32_16x16x32_bf16(af1, bw[g][1], acc[mt][g], 0, 0, 0);
                acc[mt][g] = __builtin_amdgcn_mfma_f32_16x16x32_bf16(af2, bw[g][2], acc[mt][g], 0, 0, 0);
            }
        }
        __syncthreads();   // all Xs reads done before h overwrite

        // ---- 5. LSTM elementwise (fast-rcp transcendentals); h -> Xs ----
#pragma unroll
        for (int mt = 0; mt < 2; ++mt) {
            int abase = gang*32 + mt*16 + kb*4;
#pragma unroll
            for (int r = 0; r < 4; ++r) {
                float cn = fsigmoid(acc[mt][1][r]) * cs[mt][r]
                         + fsigmoid(acc[mt][0][r]) * ftanh(acc[mt][2][r]);
                float hn = fsigmoid(acc[mt][3][r]) * ftanh(cn);
                cs[mt][r] = cn;
                Xs[(abase + r)*XSTRIDE + 16 + nh] = f2bf(hn);
            }
        }
        __syncthreads();

        // ---- 6. LN2 (split 8-way) + folded h2p -> out (write-through) ----
        {
            int a = tid >> 3, p = tid & 7;
            bf16x8 hv = *(const bf16x8*)&Xs[a*XSTRIDE + 16 + p*8];
            float s1 = 0.f, s2 = 0.f, d0 = 0.f, d1 = 0.f;
#pragma unroll
            for (int j = 0; j < 8; ++j) {
                float f = bf2f(hv[j]);
                float2 gw = *(const float2*)&cst[C_G2 + (p*8 + j)*2];
                s1 += f; s2 += f*f;
                d0 += f*gw.x; d1 += f*gw.y;
            }
#pragma unroll
            for (int mk = 1; mk < 8; mk <<= 1) {
                s1 += __shfl_xor(s1, mk, 64);
                s2 += __shfl_xor(s2, mk, 64);
                d0 += __shfl_xor(d0, mk, 64);
                d1 += __shfl_xor(d1, mk, 64);
            }
            if (p < 2) {
                float m   = s1 * (1.f/64);
                float inv = rsqrtf(s2*(1.f/64) - m*m + LN_EPS);
                float dd  = (p == 0) ? d0 : d1;
                float val = inv*(dd - m*cst[C_SG2+p]) + cst[C_B2+p];
                __hip_atomic_store(&out[s*SLAB + (a0 + a)*2 + p], val,
                                   __ATOMIC_RELAXED, __HIP_MEMORY_SCOPE_AGENT);
            }
        }

        // ---- 7. publish progress: relaxed flag store after vmcnt drain ----
        if (s != PRED-1) {
            __syncthreads();
            if (tid == 0)
                __hip_atomic_store(&flags[bid], s+1, __ATOMIC_RELAXED,
                                   __HIP_MEMORY_SCOPE_AGENT);
        }
    }
}

extern "C" void kernel_launch(void* const* d_in, const int* in_sizes, int n_in,
                              void* d_out, int out_size, void* d_ws, size_t ws_size,
                              hipStream_t stream) {
    const float* traj  = (const float*)d_in[0];
    // d_in[1] = traj_rel (unused)
    const float* dec_h = (const float*)d_in[2];
    const float* W_ih  = (const float*)d_in[3];
    const float* W_hh  = (const float*)d_in[4];
    const float* b_ih  = (const float*)d_in[5];
    const float* b_hh  = (const float*)d_in[6];
    const float* emb_W = (const float*)d_in[7];
    const float* emb_b = (const float*)d_in[8];
    const float* h2p_W = (const float*)d_in[9];
    const float* h2p_b = (const float*)d_in[10];
    const float* ln1_g = (const float*)d_in[11];
    const float* ln1_b = (const float*)d_in[12];
    const float* ln2_g = (const float*)d_in[13];
    const float* ln2_b = (const float*)d_in[14];
    float* out = (float*)d_out;
    int*   flg = (int*)d_ws;

    persist_kernel<<<NBLK, BTH, 0, stream>>>(
        traj, out, dec_h, W_ih, W_hh, b_ih, b_hh, emb_W, emb_b,
        h2p_W, h2p_b, ln1_g, ln1_b, ln2_g, ln2_b, flg);
}

// Round 15
// 312.708 us; speedup vs baseline: 3.1723x; 1.8906x over previous
//
#include <hip/hip_runtime.h>
#include <hip/hip_bf16.h>

#define NAGENTS 32768
#define SLAB    65536            // NAGENTS*2
#define SPLIT   1310720          // 20*SLAB
#define SPLIT4  327680           // SPLIT/4
#define PRED    30
#define IN_F    40
#define LN_EPS  1e-5f
#define APB     128              // agents per block
#define NBLK    (NAGENTS/APB)    // 256 = 1 block/CU -> co-resident by construction
#define BTH     1024
#define XSTRIDE 104              // shorts per agent row in Xs (96 used + 8 pad)
#define RSTR    72               // shorts per agent row in Rs (40 data + 24 zero + 8 pad)

typedef short bf16x8 __attribute__((ext_vector_type(8)));
typedef short bf16x4 __attribute__((ext_vector_type(4)));
typedef float f32x4  __attribute__((ext_vector_type(4)));

// cst float offsets — EXACT r11 layout (bias/sgW/bW in LDS, NOT registers:
// the r12 "hoist to regs" pushed the 128-reg/wave budget into scratch spills
// => 1.2 GB/step-loop traffic. Keep per-thread liveness at r11's level.)
#define C_SGW  0      // 16  : sum_f ln1g[f]*embW[e,f]
#define C_BW   16     // 16  : sum_f ln1b[f]*embW[e,f] + emb_b[e]
#define C_G2   32     // 128 : g2WT[k*2+d] = ln2g[k]*h2pW[d,k]
#define C_SG2  160    // 2
#define C_B2   162    // 2
#define C_BIAS 164    // 256 : b_ih + b_hh
#define C_TOT  420

__device__ __forceinline__ float frcp(float x){ return __builtin_amdgcn_rcpf(x); }
__device__ __forceinline__ float fsigmoid(float x){ return frcp(1.f + __expf(-x)); }
__device__ __forceinline__ float ftanh(float x){
    float t = __expf(-2.f*fabsf(x));
    float r = (1.f - t) * frcp(1.f + t);
    return copysignf(r, x);
}
__device__ __forceinline__ float lrelu(float x){ return x > 0.f ? x : 0.01f*x; }
__device__ __forceinline__ short f2bf(float x){
    unsigned u = __float_as_uint(x);
    return (short)((u + 0x7FFFu + ((u>>16)&1u)) >> 16);   // RNE
}
__device__ __forceinline__ float bf2f(short s){
    return __uint_as_float(((unsigned)(unsigned short)s) << 16);
}
__device__ __forceinline__ unsigned pk_bf16(float a, float b){
    __hip_bfloat162 h = __float22bfloat162_rn(float2{a, b});
    return *reinterpret_cast<unsigned*>(&h);
}

__global__ __launch_bounds__(BTH, 4)
void persist_kernel(const float* __restrict__ traj,
                    float* __restrict__ out,
                    const float* __restrict__ dec_h,
                    const float* __restrict__ W_ih, const float* __restrict__ W_hh,
                    const float* __restrict__ b_ih, const float* __restrict__ b_hh,
                    const float* __restrict__ emb_W, const float* __restrict__ emb_b,
                    const float* __restrict__ h2p_W, const float* __restrict__ h2p_b,
                    const float* __restrict__ ln1_g, const float* __restrict__ ln1_b,
                    const float* __restrict__ ln2_g, const float* __restrict__ ln2_b,
                    int* __restrict__ flags)   // ws: flags[b] = # steps block b completed
{
    __shared__ short Rs[APB*RSTR];      // bf16 window rows, A-layout, k-pad zeroed
    __shared__ short Xs[APB*XSTRIDE];   // bf16 A-operand [agent][k]: 0..16 x, 16..80 h, 80..96 zero
    __shared__ float Ds[APB*16];        // embedding dot outputs (r11 layout: keeps dacc dead across barriers)
    __shared__ float St[APB*2];         // LN1 stats: m, inv per agent
    __shared__ float cst[C_TOT];

    const int tid  = threadIdx.x;
    const int bid  = blockIdx.x;
    const int a0   = bid * APB;
    const int l    = tid & 63;
    const int wv   = tid >> 6;            // 0..15
    const int gang = wv >> 2;             // 0..3 : 32 agents each (gates GEMM)
    const int wvin = wv & 3;
    const int cl   = l & 15;
    const int kb   = l >> 4;
    const int nh   = wvin*16 + cl;        // gate-elem column this lane owns

    // ---- one-time folded-constant precompute (per block) ----
    if (tid < 16) {
        int e = tid;
        float s = 0.f, b = 0.f;
        for (int f = 0; f < IN_F; ++f) {
            float wf = emb_W[e*40 + f];
            s += ln1_g[f] * wf;
            b += ln1_b[f] * wf;
        }
        cst[C_SGW + e] = s;
        cst[C_BW + e]  = b + emb_b[e];
    }
    if (tid < 128) {
        int k = tid >> 1, d = tid & 1;
        cst[C_G2 + tid] = ln2_g[k] * h2p_W[d*64 + k];
    }
    if (tid < 2) {
        int d = tid;
        float s = 0.f, b = 0.f;
        for (int k = 0; k < 64; ++k) {
            float wf = h2p_W[d*64 + k];
            s += ln2_g[k] * wf;
            b += ln2_b[k] * wf;
        }
        cst[C_SG2 + d] = s;
        cst[C_B2 + d]  = b + h2p_b[d];
    }
    if (tid >= 256 && tid < 512) cst[C_BIAS + tid - 256] = b_ih[tid-256] + b_hh[tid-256];

    // ---- gates-B fragments (weights), once for all 30 steps ----
    bf16x8 bw[4][3];
#pragma unroll
    for (int g = 0; g < 4; ++g)
#pragma unroll
        for (int ks = 0; ks < 3; ++ks) {
            int n = g*64 + nh;
            bf16x8 v;
#pragma unroll
            for (int j = 0; j < 8; ++j) {
                int k = ks*32 + kb*8 + j;
                float f = 0.f;
                if (k < 16)      f = W_ih[n*16 + k];
                else if (k < 80) f = W_hh[n*64 + (k-16)];
                v[j] = f2bf(f);
            }
            bw[g][ks] = v;
        }

    // ---- embedding-B fragments: B[k=f][n=e] = ln1g[f]*embW[e,f], K-pad 0 ----
    bf16x8 ew[2];
#pragma unroll
    for (int ks = 0; ks < 2; ++ks) {
        bf16x8 v;
#pragma unroll
        for (int j = 0; j < 8; ++j) {
            int k = ks*32 + kb*8 + j;
            float f = (k < IN_F) ? ln1_g[k] * emb_W[cl*40 + k] : 0.f;
            v[j] = f2bf(f);
        }
        ew[ks] = v;
    }

    // ---- init h region of Xs from dec_h; zero pads (written once) ----
    for (int i = tid; i < APB*16; i += BTH) {
        int a = i >> 4, q = i & 15;
        float4 hv = ((const float4*)dec_h)[(a0 + a)*16 + q];
        uint2 pv{ pk_bf16(hv.x, hv.y), pk_bf16(hv.z, hv.w) };
        *(uint2*)&Xs[a*XSTRIDE + 16 + q*4] = pv;
    }
    if (tid < APB*2) {      // Xs k-pad [80,96)
        int a = tid >> 1, hf = tid & 1;
        *(bf16x8*)&Xs[a*XSTRIDE + 80 + hf*8] = bf16x8{0,0,0,0,0,0,0,0};
    }
    for (int i = tid; i < APB*3; i += BTH) {   // Rs k-pad [40,64)
        int a = i / 3, seg = i - a*3;
        *(bf16x8*)&Rs[a*RSTR + 40 + seg*8] = bf16x8{0,0,0,0,0,0,0,0};
    }

    // ---- c state fp32 in registers for all 30 steps ----
    float cs[2][4];
#pragma unroll
    for (int mt = 0; mt < 2; ++mt)
#pragma unroll
        for (int r = 0; r < 4; ++r) cs[mt][r] = 0.f;

    __syncthreads();

    for (int s = 0; s < PRED; ++s) {
        // ---- 0. wait for producer chunks (r11-exact: separate phase,
        //         <=21 acquire polls per block-step, s_sleep(1)) ----
        {
            const long Ob = (long)s*SLAB + (long)a0*IN_F - SPLIT;
            const long Oe = Ob + APB*IN_F;    // exclusive
            if (Oe > 0) {
                long o0 = Ob < 0 ? 0 : Ob;
                int i0 = (int)(o0 >> 8);
                int i1 = (int)((Oe - 1) >> 8);
                for (int i = i0 + tid; i <= i1; i += BTH) {
                    int t = i >> 8, p = i & 255;
                    while (__hip_atomic_load(&flags[p], __ATOMIC_ACQUIRE,
                                             __HIP_MEMORY_SCOPE_AGENT) < t + 1)
                        __builtin_amdgcn_s_sleep(1);
                }
            }
        }
        __syncthreads();

        // ---- 1. stage rows: poll-free float4 loads -> packed bf16 Rs ----
        {
            const int Gb4 = s*(SLAB/4) + bid*(APB*IN_F/4);
            for (int i = tid; i < APB*IN_F/4; i += BTH) {    // 1280 float4
                int a = i / 10, f4 = i - a*10;
                int G4 = Gb4 + i;
                float4 v = (G4 < SPLIT4) ? ((const float4*)traj)[G4]
                                         : ((const float4*)out)[G4 - SPLIT4];
                uint2 pv{ pk_bf16(v.x, v.y), pk_bf16(v.z, v.w) };
                *(uint2*)&Rs[a*RSTR + f4*4] = pv;
            }
        }
        __syncthreads();

        // ---- 2a. embedding GEMM (waves 0-7) -> Ds (r11 layout) ----
        if (wv < 8) {
            f32x4 dacc = f32x4{0.f, 0.f, 0.f, 0.f};
            const short* base = &Rs[(wv*16 + cl)*RSTR + kb*8];
            bf16x8 a0f = *(const bf16x8*)(base);        // k 0..31
            bf16x8 a1f = *(const bf16x8*)(base + 32);   // k 32..63
            dacc = __builtin_amdgcn_mfma_f32_16x16x32_bf16(a0f, ew[0], dacc, 0, 0, 0);
            dacc = __builtin_amdgcn_mfma_f32_16x16x32_bf16(a1f, ew[1], dacc, 0, 0, 0);
#pragma unroll
            for (int r = 0; r < 4; ++r)
                Ds[(wv*16 + kb*4 + r)*16 + cl] = dacc[r];
        } else {
        // ---- 2b. LN1 stats (waves 8-15): 4 thr/agent over bf16 rows ----
            int t2 = tid - 512;
            int a = t2 >> 2, p = t2 & 3;
            const bf16x8* rp = (const bf16x8*)&Rs[a*RSTR + p*16];
            bf16x8 v0 = rp[0], v1 = rp[1];    // k-pad zeros don't affect sums
            float s1 = 0.f, s2 = 0.f;
#pragma unroll
            for (int j = 0; j < 8; ++j) {
                float f0 = bf2f(v0[j]), f1 = bf2f(v1[j]);
                s1 += f0 + f1; s2 += f0*f0 + f1*f1;
            }
            s1 += __shfl_xor(s1, 1, 64); s2 += __shfl_xor(s2, 1, 64);
            s1 += __shfl_xor(s1, 2, 64); s2 += __shfl_xor(s2, 2, 64);
            if (p == 0) {
                float m = s1 * (1.f/IN_F);
                St[a*2]   = m;
                St[a*2+1] = rsqrtf(s2*(1.f/IN_F) - m*m + LN_EPS);
            }
        }
        __syncthreads();

        // ---- 3. embedding epilogue (all threads, from Ds/St/cst) -> Xs x ----
        {
            int a = tid >> 3, p = tid & 7, e0 = p*2;
            float m = St[a*2], inv = St[a*2+1];
            float D0 = Ds[a*16 + e0], D1 = Ds[a*16 + e0 + 1];
            float x0 = inv*(D0 - m*cst[C_SGW+e0  ]) + cst[C_BW+e0  ];
            float x1 = inv*(D1 - m*cst[C_SGW+e0+1]) + cst[C_BW+e0+1];
            unsigned pv = pk_bf16(lrelu(x0), lrelu(x1));
            *(unsigned*)&Xs[a*XSTRIDE + e0] = pv;
        }
        __syncthreads();

        // ---- 4. gates GEMM via MFMA: gang handles 32 agents, 2 M-tiles ----
        f32x4 acc[2][4];
#pragma unroll
        for (int g = 0; g < 4; ++g) {
            float bb = cst[C_BIAS + g*64 + nh];
            acc[0][g] = f32x4{bb, bb, bb, bb};
            acc[1][g] = f32x4{bb, bb, bb, bb};
        }
#pragma unroll
        for (int mt = 0; mt < 2; ++mt) {
            const short* base = &Xs[(gang*32 + mt*16 + cl)*XSTRIDE + kb*8];
            bf16x8 af0 = *(const bf16x8*)(base);
            bf16x8 af1 = *(const bf16x8*)(base + 32);
            bf16x8 af2 = *(const bf16x8*)(base + 64);
#pragma unroll
            for (int g = 0; g < 4; ++g) {
                acc[mt][g] = __builtin_amdgcn_mfma_f32_16x16x32_bf16(af0, bw[g][0], acc[mt][g], 0, 0, 0);
                acc[mt][g] = __builtin_amdgcn_mfma_f32_16x16x32_bf16(af1, bw[g][1], acc[mt][g], 0, 0, 0);
                acc[mt][g] = __builtin_amdgcn_mfma_f32_16x16x32_bf16(af2, bw[g][2], acc[mt][g], 0, 0, 0);
            }
        }
        __syncthreads();   // all Xs reads done before h overwrite

        // ---- 5. LSTM elementwise (fast-rcp transcendentals); h -> Xs ----
#pragma unroll
        for (int mt = 0; mt < 2; ++mt) {
            int abase = gang*32 + mt*16 + kb*4;
#pragma unroll
            for (int r = 0; r < 4; ++r) {
                float cn = fsigmoid(acc[mt][1][r]) * cs[mt][r]
                         + fsigmoid(acc[mt][0][r]) * ftanh(acc[mt][2][r]);
                float hn = fsigmoid(acc[mt][3][r]) * ftanh(cn);
                cs[mt][r] = cn;
                Xs[(abase + r)*XSTRIDE + 16 + nh] = f2bf(hn);
            }
        }
        __syncthreads();

        // ---- 6. LN2 (split 8-way) + folded h2p -> out (write-through) ----
        {
            int a = tid >> 3, p = tid & 7;
            bf16x8 hv = *(const bf16x8*)&Xs[a*XSTRIDE + 16 + p*8];
            float s1 = 0.f, s2 = 0.f, d0 = 0.f, d1 = 0.f;
#pragma unroll
            for (int j = 0; j < 8; ++j) {
                float f = bf2f(hv[j]);
                float2 gw = *(const float2*)&cst[C_G2 + (p*8 + j)*2];
                s1 += f; s2 += f*f;
                d0 += f*gw.x; d1 += f*gw.y;
            }
#pragma unroll
            for (int mk = 1; mk < 8; mk <<= 1) {
                s1 += __shfl_xor(s1, mk, 64);
                s2 += __shfl_xor(s2, mk, 64);
                d0 += __shfl_xor(d0, mk, 64);
                d1 += __shfl_xor(d1, mk, 64);
            }
            if (p < 2) {
                float m   = s1 * (1.f/64);
                float inv = rsqrtf(s2*(1.f/64) - m*m + LN_EPS);
                float dd  = (p == 0) ? d0 : d1;
                float val = inv*(dd - m*cst[C_SG2+p]) + cst[C_B2+p];
                __hip_atomic_store(&out[s*SLAB + (a0 + a)*2 + p], val,
                                   __ATOMIC_RELAXED, __HIP_MEMORY_SCOPE_AGENT);
            }
        }

        // ---- 7. publish progress: relaxed flag store after vmcnt drain ----
        if (s != PRED-1) {
            __syncthreads();
            if (tid == 0)
                __hip_atomic_store(&flags[bid], s+1, __ATOMIC_RELAXED,
                                   __HIP_MEMORY_SCOPE_AGENT);
        }
    }
}

extern "C" void kernel_launch(void* const* d_in, const int* in_sizes, int n_in,
                              void* d_out, int out_size, void* d_ws, size_t ws_size,
                              hipStream_t stream) {
    const float* traj  = (const float*)d_in[0];
    // d_in[1] = traj_rel (unused)
    const float* dec_h = (const float*)d_in[2];
    const float* W_ih  = (const float*)d_in[3];
    const float* W_hh  = (const float*)d_in[4];
    const float* b_ih  = (const float*)d_in[5];
    const float* b_hh  = (const float*)d_in[6];
    const float* emb_W = (const float*)d_in[7];
    const float* emb_b = (const float*)d_in[8];
    const float* h2p_W = (const float*)d_in[9];
    const float* h2p_b = (const float*)d_in[10];
    const float* ln1_g = (const float*)d_in[11];
    const float* ln1_b = (const float*)d_in[12];
    const float* ln2_g = (const float*)d_in[13];
    const float* ln2_b = (const float*)d_in[14];
    float* out = (float*)d_out;
    int*   flg = (int*)d_ws;

    persist_kernel<<<NBLK, BTH, 0, stream>>>(
        traj, out, dec_h, W_ih, W_hh, b_ih, b_hh, emb_W, emb_b,
        h2p_W, h2p_b, ln1_g, ln1_b, ln2_g, ln2_b, flg);
}